// Round 9
// baseline (407.528 us; speedup 1.0000x reference)
//
#include <hip/hip_runtime.h>
#include <hip/hip_bf16.h>

// Problem constants
#define NB 4
#define NC 256
#define ND 32
#define WH 1024          // W*H
#define DWH 32768        // D*W*H
#define KTOT 1024        // 4 modalities * 256 channels

typedef __attribute__((ext_vector_type(8))) short short8;
typedef __attribute__((ext_vector_type(4))) float f32x4;

static __device__ __forceinline__ unsigned short f32_to_bf16(float f) {
    unsigned u = __builtin_bit_cast(unsigned, f);
    u = u + 0x7fff + ((u >> 16) & 1);   // round-to-nearest-even
    return (unsigned short)(u >> 16);
}

static __device__ __forceinline__ unsigned pack_bf16x2(float lo, float hi) {
    return (unsigned)f32_to_bf16(lo) | ((unsigned)f32_to_bf16(hi) << 16);
}

// ---------------------------------------------------------------------------
// Kernel 1: adaptive_avg_pool3d(x,(D,1,1)) == mean over W,H -> pooled[b][c][m][d]
// ---------------------------------------------------------------------------
__global__ __launch_bounds__(256) void pool_kernel(
    const float* __restrict__ i0, const float* __restrict__ i1,
    const float* __restrict__ i2, const float* __restrict__ i3,
    float* __restrict__ pooled)
{
    int bid = blockIdx.x;            // (b*NC + c)*4 + m
    int m   = bid & 3;
    int bc  = bid >> 2;              // b*NC + c
    const float* src = (m == 0 ? i0 : m == 1 ? i1 : m == 2 ? i2 : i3)
                       + (size_t)bc * DWH;
    int t = threadIdx.x;
    int wave = t >> 6, lane = t & 63;

    for (int d = wave; d < ND; d += 4) {
        const float4* row = (const float4*)(src + (size_t)d * WH);
        float s = 0.f;
        #pragma unroll
        for (int j = 0; j < 4; ++j) {
            float4 v = row[lane + 64 * j];
            s += v.x + v.y + v.z + v.w;
        }
        #pragma unroll
        for (int off = 32; off; off >>= 1) s += __shfl_down(s, off, 64);
        if (lane == 0) pooled[bc * 128 + m * 32 + d] = s * (1.0f / 1024.0f);
    }
}

// ---------------------------------------------------------------------------
// Kernel 2: attention weights + effective GEMM A-matrix + effective bias.
// ---------------------------------------------------------------------------
__global__ __launch_bounds__(64) void attn_kernel(
    const float* __restrict__ pooled,
    const float* __restrict__ Wq, const float* __restrict__ bq,
    const float* __restrict__ Wk, const float* __restrict__ bk,
    const float* __restrict__ Wc, const float* __restrict__ bcv,
    unsigned short* __restrict__ Amat, float* __restrict__ beff)
{
    int bc_idx = blockIdx.x;             // b*NC + c
    int lane = threadIdx.x;
    int e = lane & 31;
    const float* P = pooled + bc_idx * 128;

    float q = 0.f, kv[4] = {0.f, 0.f, 0.f, 0.f};
    for (int d = 0; d < 32; ++d) {
        float pq = P[d];
        float wq = Wq[e * 32 + d], wk = Wk[e * 32 + d];
        q += pq * wq;
        #pragma unroll
        for (int m = 0; m < 4; ++m) kv[m] += P[m * 32 + d] * wk;
    }
    q += bq[e];
    #pragma unroll
    for (int m = 0; m < 4; ++m) kv[m] += bk[e];

    float lg[4];
    #pragma unroll
    for (int m = 0; m < 4; ++m) {
        float p = q * kv[m];
        #pragma unroll
        for (int off = 16; off; off >>= 1) p += __shfl_xor(p, off, 32);
        lg[m] = p * 0.17677669529663687f;    // 1/sqrt(32)
    }
    float mx = fmaxf(fmaxf(lg[0], lg[1]), fmaxf(lg[2], lg[3]));
    float ex[4], s = 0.f;
    #pragma unroll
    for (int m = 0; m < 4; ++m) { ex[m] = __expf(lg[m] - mx); s += ex[m]; }
    float a[4];
    #pragma unroll
    for (int m = 0; m < 4; ++m) a[m] = ex[m] / s;

    int c = bc_idx & 255;
    if (lane == 0) {
        float be = 0.f;
        #pragma unroll
        for (int m = 0; m < 4; ++m) be += a[m] * bcv[m * NC + c];
        beff[bc_idx] = be;
    }
    unsigned short* Arow = Amat + (size_t)bc_idx * KTOT;
    #pragma unroll
    for (int j = 0; j < 16; ++j) {
        int k = j * 64 + lane;
        int m = k >> 8, cin = k & 255;
        float v = a[m] * Wc[(m * NC + c) * NC + cin];
        Arow[k] = f32_to_bf16(v);
    }
}

// ---------------------------------------------------------------------------
// Kernel 3: per-batch GEMM, 256x256 tile, 8 waves (2Mx4N, wave-tile 128x64),
// 2 phases per K-tile of 64. A: LDS dbuf staged 1 tile ahead (gload_lds,
// pre-swizzled source). B: SINGLE reg buffer v[8] float4; convert v=B(t+1)
// then reuse the same regs to issue B(t+2) (WAR-safe, in-order issue).
// vmcnt(8) only at tile boundary -> B(t+2) stays in flight. A-requests
// halved vs BN=128 (256 MB total), 96 KB vmem per K-tile for 2x the MFMA.
// ---------------------------------------------------------------------------
#define BM 256
#define BN 256
#define BK 64

static __device__ __forceinline__ int swz(int row, int chunk) {
    // ushort units: row stride 64 ushorts (=128B), chunk = 8 ushorts (=16B)
    return row * 64 + ((chunk ^ (row & 7)) << 3);
}

#define K_TILE(T)                                                             \
  {                                                                           \
    const short* Acur_ = As + ((T) & 1) * (BM * BK);                          \
    const short* Bcur_ = Bs + ((T) & 1) * (BN * BK);                          \
    short* Anx_ = As + (((T) + 1) & 1) * (BM * BK);                           \
    short* Bnx_ = Bs + (((T) + 1) & 1) * (BN * BK);                           \
    /* ---- phase 1: kk=0 ---- */                                             \
    {                                                                         \
      short8 af_[8], bf_[4];                                                  \
      _Pragma("unroll")                                                       \
      for (int mi_ = 0; mi_ < 8; ++mi_)                                       \
        af_[mi_] = *(const short8*)(&Acur_[swz(wr * 128 + mi_ * 16 + lrow, lk)]); \
      _Pragma("unroll")                                                       \
      for (int ni_ = 0; ni_ < 4; ++ni_)                                       \
        bf_[ni_] = *(const short8*)(&Bcur_[swz(wc * 64 + ni_ * 16 + lrow, lk)]); \
      int ja_ = ((T) + 1 < 16) ? (T) + 1 : 15;                                \
      _Pragma("unroll")                                                       \
      for (int p_ = 0; p_ < 4; ++p_)                                          \
        __builtin_amdgcn_global_load_lds(                                     \
            (const __attribute__((address_space(1))) unsigned int*)           \
                (asrc + (size_t)p_ * 8 * KTOT + ja_ * BK),                    \
            (__attribute__((address_space(3))) unsigned int*)                 \
                (Anx_ + (wave * 32 + p_ * 8) * 64),                           \
            16, 0, 0);                                                        \
      __builtin_amdgcn_sched_barrier(0);                                      \
      __builtin_amdgcn_s_setprio(1);                                          \
      _Pragma("unroll")                                                       \
      for (int mi_ = 0; mi_ < 8; ++mi_)                                       \
        _Pragma("unroll")                                                     \
        for (int ni_ = 0; ni_ < 4; ++ni_)                                     \
          acc[mi_][ni_] = __builtin_amdgcn_mfma_f32_16x16x32_bf16(            \
              af_[mi_], bf_[ni_], acc[mi_][ni_], 0, 0, 0);                    \
      __builtin_amdgcn_s_setprio(0);                                          \
      __builtin_amdgcn_s_barrier();                                           \
      __builtin_amdgcn_sched_barrier(0);                                      \
    }                                                                         \
    /* ---- phase 2: kk=1 ---- */                                             \
    {                                                                         \
      short8 af_[8], bf_[4];                                                  \
      _Pragma("unroll")                                                       \
      for (int mi_ = 0; mi_ < 8; ++mi_)                                       \
        af_[mi_] = *(const short8*)(&Acur_[swz(wr * 128 + mi_ * 16 + lrow, 4 + lk)]); \
      _Pragma("unroll")                                                       \
      for (int ni_ = 0; ni_ < 4; ++ni_)                                       \
        bf_[ni_] = *(const short8*)(&Bcur_[swz(wc * 64 + ni_ * 16 + lrow, 4 + lk)]); \
      /* convert v = B(T+1), issued one full tile ago */                      \
      uint4 pk_[4];                                                           \
      _Pragma("unroll")                                                       \
      for (int i_ = 0; i_ < 4; ++i_)                                          \
        pk_[i_] = (uint4){                                                    \
            pack_bf16x2(((const float*)&v[0])[i_], ((const float*)&v[1])[i_]),\
            pack_bf16x2(((const float*)&v[2])[i_], ((const float*)&v[3])[i_]),\
            pack_bf16x2(((const float*)&v[4])[i_], ((const float*)&v[5])[i_]),\
            pack_bf16x2(((const float*)&v[6])[i_], ((const float*)&v[7])[i_])};\
      {  /* reuse v: issue B(T+2) (8 vmem, newest) */                         \
        int jb_ = ((T) + 2 < 16) ? (T) + 2 : 15;                              \
        int m_ = jb_ >> 2, cb_ = (jb_ & 3) * 64;                              \
        const float* Bb_ = (m_ == 0 ? i0 : m_ == 1 ? i1 : m_ == 2 ? i2 : i3)  \
                           + ((size_t)b * NC + cb_) * DWH + x0;               \
        _Pragma("unroll")                                                     \
        for (int j_ = 0; j_ < 8; ++j_)                                        \
          v[j_] = *(const float4*)(Bb_ + (size_t)(kb + j_) * DWH + xq * 4);   \
      }                                                                       \
      _Pragma("unroll")                                                       \
      for (int i_ = 0; i_ < 4; ++i_)                                          \
        *(uint4*)(&Bnx_[swz(xq * 4 + i_, kh)]) = pk_[i_];                     \
      __builtin_amdgcn_sched_barrier(0);                                      \
      __builtin_amdgcn_s_setprio(1);                                          \
      _Pragma("unroll")                                                       \
      for (int mi_ = 0; mi_ < 8; ++mi_)                                       \
        _Pragma("unroll")                                                     \
        for (int ni_ = 0; ni_ < 4; ++ni_)                                     \
          acc[mi_][ni_] = __builtin_amdgcn_mfma_f32_16x16x32_bf16(            \
              af_[mi_], bf_[ni_], acc[mi_][ni_], 0, 0, 0);                    \
      __builtin_amdgcn_s_setprio(0);                                          \
      /* tile boundary: drain A(T+1) + own ds_writes; keep B(T+2) in flight */\
      asm volatile("s_waitcnt vmcnt(8) lgkmcnt(0)" ::: "memory");             \
      __builtin_amdgcn_s_barrier();                                           \
      __builtin_amdgcn_sched_barrier(0);                                      \
    }                                                                         \
  }

__global__ __launch_bounds__(512, 2) void gemm_kernel(
    const float* __restrict__ i0, const float* __restrict__ i1,
    const float* __restrict__ i2, const float* __restrict__ i3,
    const unsigned short* __restrict__ Amat,
    const float* __restrict__ beff,
    float* __restrict__ out)
{
    __shared__ __align__(16) short As[2 * BM * BK];   // 64KB A dbuf
    __shared__ __align__(16) short Bs[2 * BN * BK];   // 64KB B dbuf

    // XCD-aware bijective swizzle: 512 blocks, 8 XCDs, 64 per XCD
    int raw = blockIdx.x;
    int sb  = (raw & 7) * 64 + (raw >> 3);
    int xt = sb & 127;               // x-tile (adjacent tiles share A in L2)
    int b  = sb >> 7;                // batch
    int x0 = xt * BN;

    const unsigned short* Ab = Amat + (size_t)b * NC * KTOT;  // full 256 rows

    int t = threadIdx.x;
    int wave = t >> 6, lane = t & 63;
    int wr = wave >> 2, wc = wave & 3;      // 2M x 4N wave grid
    int lrow = lane & 15, lk = lane >> 4;

    f32x4 acc[8][4];
    #pragma unroll
    for (int mi = 0; mi < 8; ++mi)
        #pragma unroll
        for (int ni = 0; ni < 4; ++ni)
            acc[mi][ni] = (f32x4){0.f, 0.f, 0.f, 0.f};

    // B staging: thread t loads float4 (4 x's) for 8 consecutive k's.
    int xq = t & 63;                 // x-group (4 floats each) -> 256 x's
    int kb = (t >> 6) * 8;           // k base (0..56)
    int kh = t >> 6;                 // k-chunk index (0..7)

    // A direct-to-LDS: instr p of wave w covers rows w*32+p*8..+7;
    // lane -> row offset lane>>3, slot lane&7; source chunk pre-swizzled.
    int ar = wave * 32 + (lane >> 3);
    int aq = (lane & 7) ^ (lane >> 3);
    const unsigned short* asrc = Ab + (size_t)ar * KTOT + aq * 8;

    float4 v[8];

    // ---- prologue: A(0)->As0; B(0)->v->convert->Bs0; issue B(1)->v ----
    {
        #pragma unroll
        for (int p = 0; p < 4; ++p)
            __builtin_amdgcn_global_load_lds(
                (const __attribute__((address_space(1))) unsigned int*)
                    (asrc + (size_t)p * 8 * KTOT),
                (__attribute__((address_space(3))) unsigned int*)
                    (As + (wave * 32 + p * 8) * 64),
                16, 0, 0);
        const float* Bb = i0 + (size_t)b * NC * DWH + x0;   // tile0: m=0,cb=0
        #pragma unroll
        for (int j = 0; j < 8; ++j)
            v[j] = *(const float4*)(Bb + (size_t)(kb + j) * DWH + xq * 4);
        uint4 pk[4];
        #pragma unroll
        for (int i = 0; i < 4; ++i)
            pk[i] = (uint4){
                pack_bf16x2(((const float*)&v[0])[i], ((const float*)&v[1])[i]),
                pack_bf16x2(((const float*)&v[2])[i], ((const float*)&v[3])[i]),
                pack_bf16x2(((const float*)&v[4])[i], ((const float*)&v[5])[i]),
                pack_bf16x2(((const float*)&v[6])[i], ((const float*)&v[7])[i])};
        const float* Bb1 = i0 + ((size_t)b * NC + 64) * DWH + x0;  // tile1
        #pragma unroll
        for (int j = 0; j < 8; ++j)
            v[j] = *(const float4*)(Bb1 + (size_t)(kb + j) * DWH + xq * 4);
        #pragma unroll
        for (int i = 0; i < 4; ++i)
            *(uint4*)(&Bs[swz(xq * 4 + i, kh)]) = pk[i];
        asm volatile("s_waitcnt vmcnt(8) lgkmcnt(0)" ::: "memory");
        __builtin_amdgcn_s_barrier();
        __builtin_amdgcn_sched_barrier(0);
    }

    #pragma unroll 1
    for (int T = 0; T < 16; ++T) {
        K_TILE(T);
    }

    // ---- epilogue: add bias, store fp32 ----
    // C/D layout (16x16x32): col = lane&15, row = (lane>>4)*4 + reg
    const float* beff_b = beff + b * NC;
    float* outb = out + (size_t)b * NC * DWH + x0;
    #pragma unroll
    for (int mi = 0; mi < 8; ++mi) {
        #pragma unroll
        for (int r4 = 0; r4 < 4; ++r4) {
            int row = wr * 128 + mi * 16 + lk * 4 + r4;
            float bias = beff_b[row];
            float* orow = outb + (size_t)row * DWH;
            #pragma unroll
            for (int ni = 0; ni < 4; ++ni) {
                int col = wc * 64 + ni * 16 + lrow;
                orow[col] = acc[mi][ni][r4] + bias;
            }
        }
    }
}

// ---------------------------------------------------------------------------
extern "C" void kernel_launch(void* const* d_in, const int* in_sizes, int n_in,
                              void* d_out, int out_size, void* d_ws, size_t ws_size,
                              hipStream_t stream) {
    const float* m1 = (const float*)d_in[0];
    const float* m2 = (const float*)d_in[1];
    const float* m3 = (const float*)d_in[2];
    const float* m4 = (const float*)d_in[3];
    const float* Wq = (const float*)d_in[4];
    const float* bq = (const float*)d_in[5];
    const float* Wk = (const float*)d_in[6];
    const float* bk = (const float*)d_in[7];
    const float* Wc = (const float*)d_in[8];
    const float* bcv = (const float*)d_in[9];
    float* out = (float*)d_out;

    float* pooled        = (float*)d_ws;                                // 512 KB
    unsigned short* Amat = (unsigned short*)((char*)d_ws + 524288);     // 2 MB
    float* beff          = (float*)((char*)d_ws + 524288 + 2097152);    // 4 KB

    pool_kernel<<<NB * NC * 4, 256, 0, stream>>>(m1, m2, m3, m4, pooled);
    attn_kernel<<<NB * NC, 64, 0, stream>>>(pooled, Wq, bq, Wk, bk, Wc, bcv,
                                            Amat, beff);
    gemm_kernel<<<NB * (DWH / BN), 512, 0, stream>>>(
        m1, m2, m3, m4, Amat, beff, out);
}

// Round 10
// 254.180 us; speedup vs baseline: 1.6033x; 1.6033x over previous
//
#include <hip/hip_runtime.h>
#include <hip/hip_bf16.h>

// Problem constants
#define NB 4
#define NC 256
#define ND 32
#define WH 1024          // W*H
#define DWH 32768        // D*W*H
#define KTOT 1024        // 4 modalities * 256 channels

typedef __attribute__((ext_vector_type(8))) short short8;
typedef __attribute__((ext_vector_type(4))) float f32x4;

static __device__ __forceinline__ unsigned short f32_to_bf16(float f) {
    unsigned u = __builtin_bit_cast(unsigned, f);
    u = u + 0x7fff + ((u >> 16) & 1);   // round-to-nearest-even
    return (unsigned short)(u >> 16);
}

// HW-packed convert: v_cvt_pk_bf16_f32 (1 instr per pair) vs ~8 VALU manual.
static __device__ __forceinline__ unsigned pack_bf16x2(float lo, float hi) {
    __hip_bfloat162 h = __float22bfloat162_rn(make_float2(lo, hi));
    unsigned u;
    __builtin_memcpy(&u, &h, 4);
    return u;
}

// ---------------------------------------------------------------------------
// Kernel 1: adaptive_avg_pool3d(x,(D,1,1)) == mean over W,H -> pooled[b][c][m][d]
// ---------------------------------------------------------------------------
__global__ __launch_bounds__(256) void pool_kernel(
    const float* __restrict__ i0, const float* __restrict__ i1,
    const float* __restrict__ i2, const float* __restrict__ i3,
    float* __restrict__ pooled)
{
    int bid = blockIdx.x;            // (b*NC + c)*4 + m
    int m   = bid & 3;
    int bc  = bid >> 2;              // b*NC + c
    const float* src = (m == 0 ? i0 : m == 1 ? i1 : m == 2 ? i2 : i3)
                       + (size_t)bc * DWH;
    int t = threadIdx.x;
    int wave = t >> 6, lane = t & 63;

    for (int d = wave; d < ND; d += 4) {
        const float4* row = (const float4*)(src + (size_t)d * WH);
        float s = 0.f;
        #pragma unroll
        for (int j = 0; j < 4; ++j) {
            float4 v = row[lane + 64 * j];
            s += v.x + v.y + v.z + v.w;
        }
        #pragma unroll
        for (int off = 32; off; off >>= 1) s += __shfl_down(s, off, 64);
        if (lane == 0) pooled[bc * 128 + m * 32 + d] = s * (1.0f / 1024.0f);
    }
}

// ---------------------------------------------------------------------------
// Kernel 2: attention weights + effective GEMM A-matrix + effective bias.
// ---------------------------------------------------------------------------
__global__ __launch_bounds__(64) void attn_kernel(
    const float* __restrict__ pooled,
    const float* __restrict__ Wq, const float* __restrict__ bq,
    const float* __restrict__ Wk, const float* __restrict__ bk,
    const float* __restrict__ Wc, const float* __restrict__ bcv,
    unsigned short* __restrict__ Amat, float* __restrict__ beff)
{
    int bc_idx = blockIdx.x;             // b*NC + c
    int lane = threadIdx.x;
    int e = lane & 31;
    const float* P = pooled + bc_idx * 128;

    float q = 0.f, kv[4] = {0.f, 0.f, 0.f, 0.f};
    for (int d = 0; d < 32; ++d) {
        float pq = P[d];
        float wq = Wq[e * 32 + d], wk = Wk[e * 32 + d];
        q += pq * wq;
        #pragma unroll
        for (int m = 0; m < 4; ++m) kv[m] += P[m * 32 + d] * wk;
    }
    q += bq[e];
    #pragma unroll
    for (int m = 0; m < 4; ++m) kv[m] += bk[e];

    float lg[4];
    #pragma unroll
    for (int m = 0; m < 4; ++m) {
        float p = q * kv[m];
        #pragma unroll
        for (int off = 16; off; off >>= 1) p += __shfl_xor(p, off, 32);
        lg[m] = p * 0.17677669529663687f;    // 1/sqrt(32)
    }
    float mx = fmaxf(fmaxf(lg[0], lg[1]), fmaxf(lg[2], lg[3]));
    float ex[4], s = 0.f;
    #pragma unroll
    for (int m = 0; m < 4; ++m) { ex[m] = __expf(lg[m] - mx); s += ex[m]; }
    float a[4];
    #pragma unroll
    for (int m = 0; m < 4; ++m) a[m] = ex[m] / s;

    int c = bc_idx & 255;
    if (lane == 0) {
        float be = 0.f;
        #pragma unroll
        for (int m = 0; m < 4; ++m) be += a[m] * bcv[m * NC + c];
        beff[bc_idx] = be;
    }
    unsigned short* Arow = Amat + (size_t)bc_idx * KTOT;
    #pragma unroll
    for (int j = 0; j < 16; ++j) {
        int k = j * 64 + lane;
        int m = k >> 8, cin = k & 255;
        float v = a[m] * Wc[(m * NC + c) * NC + cin];
        Arow[k] = f32_to_bf16(v);
    }
}

// ---------------------------------------------------------------------------
// Kernel 3: per-batch GEMM. R6 structure (best measured: single-buffered
// 32KB LDS, VGPR~84, 3-4 blocks/CU) + HW cvt_pk for the B convert.
//   Per iter: s_barrier (no drain) ; issue A-lds(it) [4 vmem, FIRST] ;
//   convert v=B(it) via v_cvt_pk_bf16_f32 ; issue B(it+1) [8 vmem] ;
//   ds_write B(it) ; s_waitcnt vmcnt(8) lgkmcnt(0) ; s_barrier ; 32 MFMA.
// ---------------------------------------------------------------------------
#define BM 128
#define BN 128
#define BK 64

static __device__ __forceinline__ int swz(int row, int chunk) {
    // ushort units: row stride 64 ushorts (=128B), chunk = 8 ushorts (=16B)
    return row * 64 + ((chunk ^ (row & 7)) << 3);
}

__global__ __launch_bounds__(256, 3) void gemm_kernel(
    const float* __restrict__ i0, const float* __restrict__ i1,
    const float* __restrict__ i2, const float* __restrict__ i3,
    const unsigned short* __restrict__ Amat,
    const float* __restrict__ beff,
    float* __restrict__ out)
{
    __shared__ __align__(16) short As[BM * BK];   // 16KB, single-buffered
    __shared__ __align__(16) short Bs[BN * BK];   // 16KB, single-buffered

    // XCD-aware bijective swizzle: 2048 blocks, 8 XCDs, 256 per XCD
    int raw = blockIdx.x;
    int sb  = (raw & 7) * 256 + (raw >> 3);
    int ot = sb & 1;                 // o-tile (fastest -> pairs share B panel)
    int xt = (sb >> 1) & 255;        // x-tile
    int b  = sb >> 9;                // batch
    int o0 = ot * BM, x0 = xt * BN;

    const unsigned short* Ab = Amat + ((size_t)b * NC + o0) * KTOT;

    int t = threadIdx.x;
    int wave = t >> 6, lane = t & 63;
    int wr = wave >> 1, wc = wave & 1;
    int lrow = lane & 15, lk = lane >> 4;

    f32x4 acc[4][4];
    #pragma unroll
    for (int mi = 0; mi < 4; ++mi)
        #pragma unroll
        for (int ni = 0; ni < 4; ++ni)
            acc[mi][ni] = (f32x4){0.f, 0.f, 0.f, 0.f};

    // B staging mapping: thread t loads float4 (4 x's) for 8 consecutive k's.
    int xq = t & 31;                 // x-group (4 floats each)
    int kb = (t >> 5) * 8;           // k base (0..56)

    // A direct-to-LDS mapping: per instr p, wave covers rows wave*32+p*8..+7,
    // lane -> row offset lane>>3, slot lane&7; source chunk pre-swizzled:
    // q = (lane&7) ^ (lane>>3)  (row&7 == lane>>3).
    int ar = wave * 32 + (lane >> 3);
    int aq = (lane & 7) ^ (lane >> 3);
    const unsigned short* asrc = Ab + (size_t)ar * KTOT + aq * 8;

    float4 v[8];

    // ---- prologue: B(0) loads in flight ----
    {
        const float* Bb = i0 + (size_t)b * NC * DWH + x0;   // it=0: m=0, cbase=0
        #pragma unroll
        for (int j = 0; j < 8; ++j)
            v[j] = *(const float4*)(Bb + (size_t)(kb + j) * DWH + xq * 4);
    }

    #pragma unroll 1
    for (int it = 0; it < KTOT / BK; ++it) {
        // ---- sync1: previous compute done; As/Bs free. Pure wave-sync,
        //      NO vmcnt drain (B(it) loads may still be in flight). ----
        __builtin_amdgcn_s_barrier();
        __builtin_amdgcn_sched_barrier(0);

        // ---- A: async direct-to-LDS for THIS iter (4 vmem, issued FIRST) ----
        #pragma unroll
        for (int p = 0; p < 4; ++p)
            __builtin_amdgcn_global_load_lds(
                (const __attribute__((address_space(1))) unsigned int*)
                    (asrc + (size_t)p * 8 * KTOT + it * BK),
                (__attribute__((address_space(3))) unsigned int*)
                    (As + (wave * 32 + p * 8) * 64),
                16, 0, 0);
        __builtin_amdgcn_sched_barrier(0);

        // ---- convert v (= B(it), arrived) -> pk via v_cvt_pk_bf16_f32 ----
        uint4 pk[4];
        #pragma unroll
        for (int i = 0; i < 4; ++i) {
            unsigned w[4];
            #pragma unroll
            for (int j = 0; j < 4; ++j)
                w[j] = pack_bf16x2(((const float*)&v[2 * j])[i],
                                   ((const float*)&v[2 * j + 1])[i]);
            pk[i] = (uint4){w[0], w[1], w[2], w[3]};
        }

        // ---- issue B loads for it+1 (8 vmem, AFTER A-lds) ----
        {
            int itn = (it < 15) ? it + 1 : 15;
            int m = itn >> 2, cbase = (itn & 3) * 64;
            const float* Bb = (m == 0 ? i0 : m == 1 ? i1 : m == 2 ? i2 : i3)
                              + ((size_t)b * NC + cbase) * DWH + x0;
            #pragma unroll
            for (int j = 0; j < 8; ++j)
                v[j] = *(const float4*)(Bb + (size_t)(kb + j) * DWH + xq * 4);
        }
        __builtin_amdgcn_sched_barrier(0);

        // ---- write converted B(it) -> Bs ----
        #pragma unroll
        for (int i = 0; i < 4; ++i)
            *(uint4*)(&Bs[swz(xq * 4 + i, t >> 5)]) = pk[i];

        // ---- sync2: A-lds drained (oldest 4 vmem), ds_writes visible;
        //      B(it+1)'s 8 vmem stay in flight across compute ----
        asm volatile("s_waitcnt vmcnt(8) lgkmcnt(0)" ::: "memory");
        __builtin_amdgcn_s_barrier();
        __builtin_amdgcn_sched_barrier(0);

        // ---- compute: 2 K-halves of 32 ----
        #pragma unroll
        for (int kk = 0; kk < 2; ++kk) {
            int q = kk * 4 + lk;
            short8 af[4], bf[4];
            #pragma unroll
            for (int mi = 0; mi < 4; ++mi) {
                int r = wr * 64 + mi * 16 + lrow;
                af[mi] = *(const short8*)(&As[swz(r, q)]);
            }
            #pragma unroll
            for (int ni = 0; ni < 4; ++ni) {
                int x = wc * 64 + ni * 16 + lrow;
                bf[ni] = *(const short8*)(&Bs[swz(x, q)]);
            }
            __builtin_amdgcn_s_setprio(1);
            #pragma unroll
            for (int mi = 0; mi < 4; ++mi)
                #pragma unroll
                for (int ni = 0; ni < 4; ++ni)
                    acc[mi][ni] = __builtin_amdgcn_mfma_f32_16x16x32_bf16(
                        af[mi], bf[ni], acc[mi][ni], 0, 0, 0);
            __builtin_amdgcn_s_setprio(0);
        }
    }

    // ---- epilogue: add bias, store fp32 ----
    // C/D layout (16x16x32): col = lane&15, row = (lane>>4)*4 + reg
    const float* beff_b = beff + b * NC + o0;
    float* outb = out + ((size_t)b * NC + o0) * DWH + x0;
    #pragma unroll
    for (int mi = 0; mi < 4; ++mi) {
        #pragma unroll
        for (int r4 = 0; r4 < 4; ++r4) {
            int row = wr * 64 + mi * 16 + lk * 4 + r4;
            float bias = beff_b[row];
            float* orow = outb + (size_t)row * DWH;
            #pragma unroll
            for (int ni = 0; ni < 4; ++ni) {
                int col = wc * 64 + ni * 16 + lrow;
                orow[col] = acc[mi][ni][r4] + bias;
            }
        }
    }
}

// ---------------------------------------------------------------------------
extern "C" void kernel_launch(void* const* d_in, const int* in_sizes, int n_in,
                              void* d_out, int out_size, void* d_ws, size_t ws_size,
                              hipStream_t stream) {
    const float* m1 = (const float*)d_in[0];
    const float* m2 = (const float*)d_in[1];
    const float* m3 = (const float*)d_in[2];
    const float* m4 = (const float*)d_in[3];
    const float* Wq = (const float*)d_in[4];
    const float* bq = (const float*)d_in[5];
    const float* Wk = (const float*)d_in[6];
    const float* bk = (const float*)d_in[7];
    const float* Wc = (const float*)d_in[8];
    const float* bcv = (const float*)d_in[9];
    float* out = (float*)d_out;

    float* pooled        = (float*)d_ws;                                // 512 KB
    unsigned short* Amat = (unsigned short*)((char*)d_ws + 524288);     // 2 MB
    float* beff          = (float*)((char*)d_ws + 524288 + 2097152);    // 4 KB

    pool_kernel<<<NB * NC * 4, 256, 0, stream>>>(m1, m2, m3, m4, pooled);
    attn_kernel<<<NB * NC, 64, 0, stream>>>(pooled, Wq, bq, Wk, bk, Wc, bcv,
                                            Amat, beff);
    gemm_kernel<<<(NB) * (NC / BM) * (DWH / BN), 256, 0, stream>>>(
        m1, m2, m3, m4, Amat, beff, out);
}

// Round 11
// 246.633 us; speedup vs baseline: 1.6524x; 1.0306x over previous
//
#include <hip/hip_runtime.h>
#include <hip/hip_bf16.h>

// Problem constants
#define NB 4
#define NC 256
#define ND 32
#define WH 1024          // W*H
#define DWH 32768        // D*W*H
#define KTOT 1024        // 4 modalities * 256 channels

typedef __attribute__((ext_vector_type(8))) short short8;
typedef __attribute__((ext_vector_type(4))) float f32x4;

static __device__ __forceinline__ unsigned short f32_to_bf16(float f) {
    unsigned u = __builtin_bit_cast(unsigned, f);
    u = u + 0x7fff + ((u >> 16) & 1);   // round-to-nearest-even
    return (unsigned short)(u >> 16);
}

// HW-packed convert: v_cvt_pk_bf16_f32 (1 instr per pair) vs ~8 VALU manual.
static __device__ __forceinline__ unsigned pack_bf16x2(float lo, float hi) {
    __hip_bfloat162 h = __float22bfloat162_rn(make_float2(lo, hi));
    unsigned u;
    __builtin_memcpy(&u, &h, 4);
    return u;
}

// ---------------------------------------------------------------------------
// Kernel 1: adaptive_avg_pool3d(x,(D,1,1)) == mean over W,H -> pooled[b][c][m][d]
// One block per (b,c,m). Thread t owns 1/8 of row d=t>>3: 32 INDEPENDENT
// float4 loads accumulated in-register (deep MLP), then one 3-shuffle
// reduction over the 8 lanes of the row group. (Old version: 4 loads ->
// waitcnt -> 6 serial shuffles per d, VGPR=16 -> latency-bound at 154 us.)
// ---------------------------------------------------------------------------
__global__ __launch_bounds__(256) void pool_kernel(
    const float* __restrict__ i0, const float* __restrict__ i1,
    const float* __restrict__ i2, const float* __restrict__ i3,
    float* __restrict__ pooled)
{
    int bid = blockIdx.x;            // (b*NC + c)*4 + m
    int m   = bid & 3;
    int bc  = bid >> 2;              // b*NC + c
    const float* src = (m == 0 ? i0 : m == 1 ? i1 : m == 2 ? i2 : i3)
                       + (size_t)bc * DWH;
    int t = threadIdx.x;
    int d   = t >> 3;                // row 0..31
    int sub = t & 7;                 // 1/8 of the row

    const float4* row = (const float4*)(src + (size_t)d * WH);
    float4 a0 = {0.f, 0.f, 0.f, 0.f}, a1 = {0.f, 0.f, 0.f, 0.f};
    #pragma unroll
    for (int j = 0; j < 16; ++j) {
        float4 u = row[sub + 8 * (2 * j)];
        float4 w = row[sub + 8 * (2 * j + 1)];
        a0.x += u.x; a0.y += u.y; a0.z += u.z; a0.w += u.w;
        a1.x += w.x; a1.y += w.y; a1.z += w.z; a1.w += w.w;
    }
    float s = (a0.x + a0.y) + (a0.z + a0.w) + (a1.x + a1.y) + (a1.z + a1.w);
    s += __shfl_down(s, 4, 64);
    s += __shfl_down(s, 2, 64);
    s += __shfl_down(s, 1, 64);
    if (sub == 0) pooled[bc * 128 + m * 32 + d] = s * (1.0f / 1024.0f);
}

// ---------------------------------------------------------------------------
// Kernel 2: attention weights + effective GEMM A-matrix + effective bias.
// ---------------------------------------------------------------------------
__global__ __launch_bounds__(64) void attn_kernel(
    const float* __restrict__ pooled,
    const float* __restrict__ Wq, const float* __restrict__ bq,
    const float* __restrict__ Wk, const float* __restrict__ bk,
    const float* __restrict__ Wc, const float* __restrict__ bcv,
    unsigned short* __restrict__ Amat, float* __restrict__ beff)
{
    int bc_idx = blockIdx.x;             // b*NC + c
    int lane = threadIdx.x;
    int e = lane & 31;
    const float* P = pooled + bc_idx * 128;

    float q = 0.f, kv[4] = {0.f, 0.f, 0.f, 0.f};
    for (int d = 0; d < 32; ++d) {
        float pq = P[d];
        float wq = Wq[e * 32 + d], wk = Wk[e * 32 + d];
        q += pq * wq;
        #pragma unroll
        for (int m = 0; m < 4; ++m) kv[m] += P[m * 32 + d] * wk;
    }
    q += bq[e];
    #pragma unroll
    for (int m = 0; m < 4; ++m) kv[m] += bk[e];

    float lg[4];
    #pragma unroll
    for (int m = 0; m < 4; ++m) {
        float p = q * kv[m];
        #pragma unroll
        for (int off = 16; off; off >>= 1) p += __shfl_xor(p, off, 32);
        lg[m] = p * 0.17677669529663687f;    // 1/sqrt(32)
    }
    float mx = fmaxf(fmaxf(lg[0], lg[1]), fmaxf(lg[2], lg[3]));
    float ex[4], s = 0.f;
    #pragma unroll
    for (int m = 0; m < 4; ++m) { ex[m] = __expf(lg[m] - mx); s += ex[m]; }
    float a[4];
    #pragma unroll
    for (int m = 0; m < 4; ++m) a[m] = ex[m] / s;

    int c = bc_idx & 255;
    if (lane == 0) {
        float be = 0.f;
        #pragma unroll
        for (int m = 0; m < 4; ++m) be += a[m] * bcv[m * NC + c];
        beff[bc_idx] = be;
    }
    unsigned short* Arow = Amat + (size_t)bc_idx * KTOT;
    #pragma unroll
    for (int j = 0; j < 16; ++j) {
        int k = j * 64 + lane;
        int m = k >> 8, cin = k & 255;
        float v = a[m] * Wc[(m * NC + c) * NC + cin];
        Arow[k] = f32_to_bf16(v);
    }
}

// ---------------------------------------------------------------------------
// Kernel 3: per-batch GEMM. R6 structure (single-buffered 32KB LDS, VGPR~84,
// 3-4 blocks/CU) + HW cvt_pk for the B convert. (155 us measured, R10.)
// ---------------------------------------------------------------------------
#define BM 128
#define BN 128
#define BK 64

static __device__ __forceinline__ int swz(int row, int chunk) {
    // ushort units: row stride 64 ushorts (=128B), chunk = 8 ushorts (=16B)
    return row * 64 + ((chunk ^ (row & 7)) << 3);
}

__global__ __launch_bounds__(256, 3) void gemm_kernel(
    const float* __restrict__ i0, const float* __restrict__ i1,
    const float* __restrict__ i2, const float* __restrict__ i3,
    const unsigned short* __restrict__ Amat,
    const float* __restrict__ beff,
    float* __restrict__ out)
{
    __shared__ __align__(16) short As[BM * BK];   // 16KB, single-buffered
    __shared__ __align__(16) short Bs[BN * BK];   // 16KB, single-buffered

    // XCD-aware bijective swizzle: 2048 blocks, 8 XCDs, 256 per XCD
    int raw = blockIdx.x;
    int sb  = (raw & 7) * 256 + (raw >> 3);
    int ot = sb & 1;                 // o-tile (fastest -> pairs share B panel)
    int xt = (sb >> 1) & 255;        // x-tile
    int b  = sb >> 9;                // batch
    int o0 = ot * BM, x0 = xt * BN;

    const unsigned short* Ab = Amat + ((size_t)b * NC + o0) * KTOT;

    int t = threadIdx.x;
    int wave = t >> 6, lane = t & 63;
    int wr = wave >> 1, wc = wave & 1;
    int lrow = lane & 15, lk = lane >> 4;

    f32x4 acc[4][4];
    #pragma unroll
    for (int mi = 0; mi < 4; ++mi)
        #pragma unroll
        for (int ni = 0; ni < 4; ++ni)
            acc[mi][ni] = (f32x4){0.f, 0.f, 0.f, 0.f};

    // B staging mapping: thread t loads float4 (4 x's) for 8 consecutive k's.
    int xq = t & 31;                 // x-group (4 floats each)
    int kb = (t >> 5) * 8;           // k base (0..56)

    // A direct-to-LDS mapping: per instr p, wave covers rows wave*32+p*8..+7,
    // lane -> row offset lane>>3, slot lane&7; source chunk pre-swizzled:
    // q = (lane&7) ^ (lane>>3)  (row&7 == lane>>3).
    int ar = wave * 32 + (lane >> 3);
    int aq = (lane & 7) ^ (lane >> 3);
    const unsigned short* asrc = Ab + (size_t)ar * KTOT + aq * 8;

    float4 v[8];

    // ---- prologue: B(0) loads in flight ----
    {
        const float* Bb = i0 + (size_t)b * NC * DWH + x0;   // it=0: m=0, cbase=0
        #pragma unroll
        for (int j = 0; j < 8; ++j)
            v[j] = *(const float4*)(Bb + (size_t)(kb + j) * DWH + xq * 4);
    }

    #pragma unroll 1
    for (int it = 0; it < KTOT / BK; ++it) {
        // ---- sync1: previous compute done; As/Bs free. Pure wave-sync,
        //      NO vmcnt drain (B(it) loads may still be in flight). ----
        __builtin_amdgcn_s_barrier();
        __builtin_amdgcn_sched_barrier(0);

        // ---- A: async direct-to-LDS for THIS iter (4 vmem, issued FIRST) ----
        #pragma unroll
        for (int p = 0; p < 4; ++p)
            __builtin_amdgcn_global_load_lds(
                (const __attribute__((address_space(1))) unsigned int*)
                    (asrc + (size_t)p * 8 * KTOT + it * BK),
                (__attribute__((address_space(3))) unsigned int*)
                    (As + (wave * 32 + p * 8) * 64),
                16, 0, 0);
        __builtin_amdgcn_sched_barrier(0);

        // ---- convert v (= B(it), arrived) -> pk via v_cvt_pk_bf16_f32 ----
        uint4 pk[4];
        #pragma unroll
        for (int i = 0; i < 4; ++i) {
            unsigned w[4];
            #pragma unroll
            for (int j = 0; j < 4; ++j)
                w[j] = pack_bf16x2(((const float*)&v[2 * j])[i],
                                   ((const float*)&v[2 * j + 1])[i]);
            pk[i] = (uint4){w[0], w[1], w[2], w[3]};
        }

        // ---- issue B loads for it+1 (8 vmem, AFTER A-lds) ----
        {
            int itn = (it < 15) ? it + 1 : 15;
            int m = itn >> 2, cbase = (itn & 3) * 64;
            const float* Bb = (m == 0 ? i0 : m == 1 ? i1 : m == 2 ? i2 : i3)
                              + ((size_t)b * NC + cbase) * DWH + x0;
            #pragma unroll
            for (int j = 0; j < 8; ++j)
                v[j] = *(const float4*)(Bb + (size_t)(kb + j) * DWH + xq * 4);
        }
        __builtin_amdgcn_sched_barrier(0);

        // ---- write converted B(it) -> Bs ----
        #pragma unroll
        for (int i = 0; i < 4; ++i)
            *(uint4*)(&Bs[swz(xq * 4 + i, t >> 5)]) = pk[i];

        // ---- sync2: A-lds drained (oldest 4 vmem), ds_writes visible;
        //      B(it+1)'s 8 vmem stay in flight across compute ----
        asm volatile("s_waitcnt vmcnt(8) lgkmcnt(0)" ::: "memory");
        __builtin_amdgcn_s_barrier();
        __builtin_amdgcn_sched_barrier(0);

        // ---- compute: 2 K-halves of 32 ----
        #pragma unroll
        for (int kk = 0; kk < 2; ++kk) {
            int q = kk * 4 + lk;
            short8 af[4], bf[4];
            #pragma unroll
            for (int mi = 0; mi < 4; ++mi) {
                int r = wr * 64 + mi * 16 + lrow;
                af[mi] = *(const short8*)(&As[swz(r, q)]);
            }
            #pragma unroll
            for (int ni = 0; ni < 4; ++ni) {
                int x = wc * 64 + ni * 16 + lrow;
                bf[ni] = *(const short8*)(&Bs[swz(x, q)]);
            }
            __builtin_amdgcn_s_setprio(1);
            #pragma unroll
            for (int mi = 0; mi < 4; ++mi)
                #pragma unroll
                for (int ni = 0; ni < 4; ++ni)
                    acc[mi][ni] = __builtin_amdgcn_mfma_f32_16x16x32_bf16(
                        af[mi], bf[ni], acc[mi][ni], 0, 0, 0);
            __builtin_amdgcn_s_setprio(0);
        }
    }

    // ---- epilogue: add bias, store fp32 ----
    // C/D layout (16x16x32): col = lane&15, row = (lane>>4)*4 + reg
    const float* beff_b = beff + b * NC + o0;
    float* outb = out + ((size_t)b * NC + o0) * DWH + x0;
    #pragma unroll
    for (int mi = 0; mi < 4; ++mi) {
        #pragma unroll
        for (int r4 = 0; r4 < 4; ++r4) {
            int row = wr * 64 + mi * 16 + lk * 4 + r4;
            float bias = beff_b[row];
            float* orow = outb + (size_t)row * DWH;
            #pragma unroll
            for (int ni = 0; ni < 4; ++ni) {
                int col = wc * 64 + ni * 16 + lrow;
                orow[col] = acc[mi][ni][r4] + bias;
            }
        }
    }
}

// ---------------------------------------------------------------------------
extern "C" void kernel_launch(void* const* d_in, const int* in_sizes, int n_in,
                              void* d_out, int out_size, void* d_ws, size_t ws_size,
                              hipStream_t stream) {
    const float* m1 = (const float*)d_in[0];
    const float* m2 = (const float*)d_in[1];
    const float* m3 = (const float*)d_in[2];
    const float* m4 = (const float*)d_in[3];
    const float* Wq = (const float*)d_in[4];
    const float* bq = (const float*)d_in[5];
    const float* Wk = (const float*)d_in[6];
    const float* bk = (const float*)d_in[7];
    const float* Wc = (const float*)d_in[8];
    const float* bcv = (const float*)d_in[9];
    float* out = (float*)d_out;

    float* pooled        = (float*)d_ws;                                // 512 KB
    unsigned short* Amat = (unsigned short*)((char*)d_ws + 524288);     // 2 MB
    float* beff          = (float*)((char*)d_ws + 524288 + 2097152);    // 4 KB

    pool_kernel<<<NB * NC * 4, 256, 0, stream>>>(m1, m2, m3, m4, pooled);
    attn_kernel<<<NB * NC, 64, 0, stream>>>(pooled, Wq, bq, Wk, bk, Wc, bcv,
                                            Amat, beff);
    gemm_kernel<<<(NB) * (NC / BM) * (DWH / BN), 256, 0, stream>>>(
        m1, m2, m3, m4, Amat, beff, out);
}